// Round 1
// baseline (1467.782 us; speedup 1.0000x reference)
//
#include <hip/hip_runtime.h>
#include <math.h>

#define BB 16
#define TT 4096
#define DM 2048
#define DC 256
#define HH 4
#define LL 4
#define DH 64
#define NJ 16   // H*L combined head/latent index, j = h*4+l
#define NTC 8   // t-chunks for U partial accumulation

// ---------------- kernel 1: prep  Q = latq@Wq+bq ; WkQ[m][j] = scale * Wk[m, h*64+d] . Qh[l,h,d] ----------------
__global__ void prep_kernel(const float* __restrict__ latq, const float* __restrict__ Wq,
                            const float* __restrict__ bq, const float* __restrict__ Wk,
                            const float* __restrict__ bk,
                            float* __restrict__ WkQ, float* __restrict__ qb) {
    __shared__ float Q[LL][DC];
    int tid = threadIdx.x;  // 256
    for (int l = 0; l < LL; ++l) {
        float s = bq[tid];
        for (int k = 0; k < DC; ++k) s = fmaf(latq[l * DC + k], Wq[k * DC + tid], s);
        Q[l][tid] = s;
    }
    __syncthreads();
    const float scale = 0.125f;  // 1/sqrt(DH)
    for (int idx = tid; idx < DM * NJ; idx += 256) {
        int m = idx >> 4, j = idx & 15, h = j >> 2, l = j & 3;
        const float* wk = Wk + (size_t)m * DC + h * DH;
        const float* qq = &Q[l][h * DH];
        float s = 0.f;
        #pragma unroll 8
        for (int d = 0; d < DH; ++d) s = fmaf(wk[d], qq[d], s);
        WkQ[m * NJ + j] = s * scale;
    }
    if (tid < NJ) {
        int j = tid, h = j >> 2, l = j & 3;
        float s = 0.f;
        for (int d = 0; d < DH; ++d) s = fmaf(bk[h * DH + d], Q[l][h * DH + d], s);
        qb[j] = s * scale;
    }
}

// ---------------- kernel 2: logits[b][j][t] = hidden[b,t,:] . WkQ[:,j] + qb[j]  (mask -> -inf) ----------------
// block = 256 threads = 4 waves; each wave computes 4 t-rows; lane = (q<<4)|ml:
// q = j-quad (j = q*4+k), ml = m-slice. WkQ row loads shared across the 4 rows.
__global__ void logits_kernel(const float* __restrict__ hidden, const int* __restrict__ mask,
                              const float* __restrict__ WkQ, const float* __restrict__ qb,
                              float* __restrict__ logits) {
    int tid = threadIdx.x;
    int wave = tid >> 6, lane = tid & 63;
    int q = lane >> 4, ml = lane & 15;
    int blk = blockIdx.x;
    int b = blk >> 8;                       // 256 blocks per batch
    int r0 = (blk & 255) * 16 + wave * 4;   // first t-row of this wave
    const size_t base = (size_t)b * TT * DM;

    float acc[4][4];
    #pragma unroll
    for (int r = 0; r < 4; ++r)
        #pragma unroll
        for (int k = 0; k < 4; ++k) acc[r][k] = 0.f;

    for (int i = 0; i < DM / 64; ++i) {     // 32 iters
        int mbase = i * 64 + ml * 4;
        float4 w4[4];
        #pragma unroll
        for (int mm = 0; mm < 4; ++mm)
            w4[mm] = *(const float4*)(WkQ + (size_t)(mbase + mm) * NJ + q * 4);
        const float* w = (const float*)w4;  // w[mm*4+k]
        #pragma unroll
        for (int r = 0; r < 4; ++r) {
            float4 h4 = *(const float4*)(hidden + base + (size_t)(r0 + r) * DM + mbase);
            const float* hp = (const float*)&h4;
            #pragma unroll
            for (int mm = 0; mm < 4; ++mm)
                #pragma unroll
                for (int k = 0; k < 4; ++k)
                    acc[r][k] = fmaf(hp[mm], w[mm * 4 + k], acc[r][k]);
        }
    }
    // reduce over the 16 m-slices (lanes sharing q)
    #pragma unroll
    for (int off = 1; off < 16; off <<= 1)
        #pragma unroll
        for (int r = 0; r < 4; ++r)
            #pragma unroll
            for (int k = 0; k < 4; ++k)
                acc[r][k] += __shfl_xor(acc[r][k], off, 64);

    if (ml == 0) {
        for (int r = 0; r < 4; ++r) {
            int t = r0 + r;
            int mv = mask[b * TT + t];
            #pragma unroll
            for (int k = 0; k < 4; ++k) {
                int j = q * 4 + k;
                float v = acc[r][k] + qb[j];
                if (mv == 0) v = -INFINITY;
                logits[((size_t)(b * NJ + j)) * TT + t] = v;
            }
        }
    }
}

// ---------------- kernel 3: in-place softmax over t for each of B*NJ rows ----------------
__global__ void softmax_kernel(float* __restrict__ logits) {
    int row = blockIdx.x;
    float* p = logits + (size_t)row * TT;
    int tid = threadIdx.x;  // 256
    float v[16];
    float mx = -INFINITY;
    #pragma unroll
    for (int k = 0; k < 16; ++k) { v[k] = p[tid + k * 256]; mx = fmaxf(mx, v[k]); }
    #pragma unroll
    for (int off = 32; off; off >>= 1) mx = fmaxf(mx, __shfl_xor(mx, off, 64));
    __shared__ float red[4], red2[4];
    int wave = tid >> 6, lane = tid & 63;
    if (lane == 0) red[wave] = mx;
    __syncthreads();
    mx = fmaxf(fmaxf(red[0], red[1]), fmaxf(red[2], red[3]));
    float s = 0.f;
    #pragma unroll
    for (int k = 0; k < 16; ++k) { v[k] = expf(v[k] - mx); s += v[k]; }
    #pragma unroll
    for (int off = 32; off; off >>= 1) s += __shfl_xor(s, off, 64);
    if (lane == 0) red2[wave] = s;
    __syncthreads();
    s = red2[0] + red2[1] + red2[2] + red2[3];
    float inv = 1.f / s;
    #pragma unroll
    for (int k = 0; k < 16; ++k) p[tid + k * 256] = v[k] * inv;
}

// ---------------- kernel 4: Up[b][tc][j][m] = sum_{t in chunk} attn[b,j,t] * hidden[b,t,m] ----------------
// grid (mc=4, tc=NTC, b); block 256; thread owns 2 consecutive m's (float2 hidden loads).
__global__ void uacc_kernel(const float* __restrict__ hidden, const float* __restrict__ attn,
                            float* __restrict__ Up) {
    int mc = blockIdx.x, tc = blockIdx.y, b = blockIdx.z;
    int tid = threadIdx.x;
    int m0 = mc * 512 + tid * 2;
    __shared__ float at[128][NJ];  // 8 KB tile of attention weights
    float acc[NJ][2];
    #pragma unroll
    for (int j = 0; j < NJ; ++j) { acc[j][0] = 0.f; acc[j][1] = 0.f; }

    for (int tile = 0; tile < 512 / 128; ++tile) {
        int tbase = tc * 512 + tile * 128;
        __syncthreads();
        #pragma unroll
        for (int k = 0; k < 8; ++k) {
            int e = tid + k * 256;
            int ttl = e >> 4, j = e & 15;
            at[ttl][j] = attn[((size_t)(b * NJ + j)) * TT + tbase + ttl];
        }
        __syncthreads();
        for (int ttl = 0; ttl < 128; ++ttl) {
            float2 h2 = *(const float2*)(hidden + ((size_t)b * TT + tbase + ttl) * DM + m0);
            float4 a0 = *(const float4*)&at[ttl][0];
            float4 a1 = *(const float4*)&at[ttl][4];
            float4 a2 = *(const float4*)&at[ttl][8];
            float4 a3 = *(const float4*)&at[ttl][12];
            const float* a = (const float*)&a0;  // a0..a3 are contiguous? not guaranteed; use per-vec
            float av[16] = {a0.x,a0.y,a0.z,a0.w, a1.x,a1.y,a1.z,a1.w,
                            a2.x,a2.y,a2.z,a2.w, a3.x,a3.y,a3.z,a3.w};
            (void)a;
            #pragma unroll
            for (int j = 0; j < NJ; ++j) {
                acc[j][0] = fmaf(av[j], h2.x, acc[j][0]);
                acc[j][1] = fmaf(av[j], h2.y, acc[j][1]);
            }
        }
    }
    for (int j = 0; j < NJ; ++j) {
        size_t o = (((size_t)b * NTC + tc) * NJ + j) * DM + m0;
        *(float2*)(Up + o) = make_float2(acc[j][0], acc[j][1]);
    }
}

// ---------------- kernel 5: epilogue per (b,l): Wv, Wo, residual, LayerNorm ----------------
__global__ void final_kernel(const float* __restrict__ Up, const float* __restrict__ Wv,
                             const float* __restrict__ bv, const float* __restrict__ Wo,
                             const float* __restrict__ bo, const float* __restrict__ latq,
                             const float* __restrict__ gamma, const float* __restrict__ beta,
                             float* __restrict__ out) {
    int blk = blockIdx.x;
    int b = blk >> 2, l = blk & 3;
    int c = threadIdx.x;  // 0..255
    int h = c >> 6;

    // stage U[b][h*4+l][:] for the 4 heads into LDS (sum the NTC partials)
    __shared__ float Ul[HH][DM];  // 32 KB
    for (int idx = c; idx < HH * DM; idx += 256) {
        int hh = idx >> 11, m = idx & (DM - 1);
        int jj = hh * 4 + l;
        float s = 0.f;
        #pragma unroll
        for (int tc = 0; tc < NTC; ++tc)
            s += Up[(((size_t)b * NTC + tc) * NJ + jj) * DM + m];
        Ul[hh][m] = s;
    }
    __syncthreads();

    // vout[c] = bv[c] + sum_m U[b][j][m] * Wv[m][c]
    float acc = bv[c];
    for (int m = 0; m < DM; m += 4) {
        acc = fmaf(Ul[h][m + 0], Wv[(size_t)(m + 0) * DC + c], acc);
        acc = fmaf(Ul[h][m + 1], Wv[(size_t)(m + 1) * DC + c], acc);
        acc = fmaf(Ul[h][m + 2], Wv[(size_t)(m + 2) * DC + c], acc);
        acc = fmaf(Ul[h][m + 3], Wv[(size_t)(m + 3) * DC + c], acc);
    }
    __shared__ float vout[DC];
    vout[c] = acc;
    __syncthreads();

    // o2[c] = bo[c] + sum_cc vout[cc] * Wo[cc][c]
    float o2 = bo[c];
    for (int cc = 0; cc < DC; cc += 4) {
        o2 = fmaf(vout[cc + 0], Wo[(cc + 0) * DC + c], o2);
        o2 = fmaf(vout[cc + 1], Wo[(cc + 1) * DC + c], o2);
        o2 = fmaf(vout[cc + 2], Wo[(cc + 2) * DC + c], o2);
        o2 = fmaf(vout[cc + 3], Wo[(cc + 3) * DC + c], o2);
    }
    float x = o2 + latq[l * DC + c];

    // LayerNorm over the 256 channels (two-pass: mean, then variance)
    int wave = c >> 6, lane = c & 63;
    __shared__ float r1[4], r2[4];
    float s1 = x;
    #pragma unroll
    for (int off = 32; off; off >>= 1) s1 += __shfl_xor(s1, off, 64);
    if (lane == 0) r1[wave] = s1;
    __syncthreads();
    float mu = (r1[0] + r1[1] + r1[2] + r1[3]) * (1.f / 256.f);
    float d = x - mu;
    float s2 = d * d;
    #pragma unroll
    for (int off = 32; off; off >>= 1) s2 += __shfl_xor(s2, off, 64);
    if (lane == 0) r2[wave] = s2;
    __syncthreads();
    float var = (r2[0] + r2[1] + r2[2] + r2[3]) * (1.f / 256.f);
    float y = d * rsqrtf(var + 1e-5f) * gamma[c] + beta[c];
    out[((size_t)b * LL + l) * DC + c] = y;
}

extern "C" void kernel_launch(void* const* d_in, const int* in_sizes, int n_in,
                              void* d_out, int out_size, void* d_ws, size_t ws_size,
                              hipStream_t stream) {
    const float* hidden = (const float*)d_in[0];
    const int*   mask   = (const int*)d_in[1];
    const float* latq   = (const float*)d_in[2];
    const float* Wq     = (const float*)d_in[3];
    const float* bq     = (const float*)d_in[4];
    const float* Wk     = (const float*)d_in[5];
    const float* bk     = (const float*)d_in[6];
    const float* Wv     = (const float*)d_in[7];
    const float* bv     = (const float*)d_in[8];
    const float* Wo     = (const float*)d_in[9];
    const float* bo     = (const float*)d_in[10];
    const float* gamma  = (const float*)d_in[11];
    const float* beta   = (const float*)d_in[12];
    float* out = (float*)d_out;

    float* ws = (float*)d_ws;
    float* WkQ    = ws;                          // 2048*16 = 32768 floats
    float* qb     = ws + 32768;                  // 16 floats (pad to 256)
    float* logits = ws + 33024;                  // B*NJ*T = 1,048,576 floats
    float* Up     = ws + 33024 + (size_t)BB * NJ * TT;  // B*NTC*NJ*DM = 4,194,304 floats

    prep_kernel<<<1, 256, 0, stream>>>(latq, Wq, bq, Wk, bk, WkQ, qb);
    logits_kernel<<<BB * TT / 16, 256, 0, stream>>>(hidden, mask, WkQ, qb, logits);
    softmax_kernel<<<BB * NJ, 256, 0, stream>>>(logits);
    uacc_kernel<<<dim3(4, NTC, BB), 256, 0, stream>>>(hidden, logits, Up);
    final_kernel<<<BB * LL, 256, 0, stream>>>(Up, Wv, bv, Wo, bo, latq, gamma, beta, out);
}